// Round 17
// baseline (2914.022 us; speedup 1.0000x reference)
//
#include <hip/hip_runtime.h>
#include <math.h>

#define TILE 256
#define KNN  64

// Theory: "np" ref = JAX reference re-run on XLA-CPU:
//   sq  = (p0+p2) + (p1+p3), pk = xk*xk rounded, NO FMA
//         (LLVM fast-math halving lowering of vector.reduce.fadd over 4 lanes)
//   dot = asc-k FMA chain (Eigen gebp microkernel)
//   d2  = (sq_i + sq_j) - 2*dot   [C1]  (fma(-2,dot,t1) is bitwise identical)
//   ties: lax.top_k stable -> bit-equal d2 ordered by ASCENDING index
// Key: sign-corrected f32 bits (monotone incl. cancellation negatives) in
// high word, local idx in low word -> lex (d2 asc, idx asc).
__global__ __launch_bounds__(64) void knn_f32_kernel(
    const float4* __restrict__ coords,
    float* __restrict__ outIdx,
    float* __restrict__ outDist,
    int S)
{
#pragma clang fp contract(off)
    __shared__ float4 cpos[TILE];
    __shared__ float  csq[TILE];
    __shared__ unsigned long long hk[KNN][65];   // [node][thread], pad 65

    const int t  = threadIdx.x;
    const int q0 = blockIdx.x * 64;
    const int q  = q0 + t;
    const int seg_start = (q0 / S) * S;   // S % 64 == 0: blocks never straddle

    const float4 x = coords[q];
    const float sqx = (x.x * x.x + x.z * x.z) + (x.y * x.y + x.w * x.w);

    for (int n = 0; n < KNN; ++n) hk[n][t] = ~0ULL;
    unsigned long long worst = ~0ULL;

    for (int c0 = 0; c0 < S; c0 += TILE) {
        __syncthreads();
        for (int j = t; j < TILE; j += 64) {
            float4 c = coords[seg_start + c0 + j];
            cpos[j] = c;
            csq[j]  = (c.x * c.x + c.z * c.z) + (c.y * c.y + c.w * c.w);
        }
        __syncthreads();

        for (int j = 0; j < TILE; j += 4) {
            unsigned long long kv[4];
#pragma unroll
            for (int m = 0; m < 4; ++m) {
                float4 c = cpos[j + m];
                float dot = __builtin_fmaf(x.w, c.w,
                            __builtin_fmaf(x.z, c.z,
                            __builtin_fmaf(x.y, c.y, x.x * c.x)));
                float t1  = sqx + csq[j + m];           // sq_i + sq_j
                float d2  = t1 - 2.0f * dot;            // C1 combine
                unsigned int b = __float_as_uint(d2);
                b ^= (unsigned int)((int)b >> 31) | 0x80000000u;  // order-preserving
                kv[m] = ((unsigned long long)b << 32) |
                        (unsigned long long)(unsigned int)(c0 + j + m);
            }
#pragma unroll
            for (int m = 0; m < 4; ++m) {
                if (kv[m] < worst) {
                    unsigned long long v = kv[m];
                    int n = 0;
                    while (true) {
                        int l = 2 * n + 1;
                        if (l >= KNN) break;
                        unsigned long long cl = hk[l][t];
                        int cbig = l;
                        if (l + 1 < KNN) {
                            unsigned long long cr = hk[l + 1][t];
                            if (cr > cl) { cl = cr; cbig = l + 1; }
                        }
                        if (v < cl) { hk[n][t] = cl; n = cbig; }
                        else break;
                    }
                    hk[n][t] = v;
                    worst = hk[0][t];
                }
            }
        }
    }

    // per-thread heapsort -> ascending (d2, idx); array position becomes rank
    for (int end = KNN - 1; end > 0; --end) {
        unsigned long long v = hk[end][t];
        hk[end][t] = hk[0][t];
        int n = 0;
        while (true) {
            int l = 2 * n + 1;
            if (l >= end) break;
            unsigned long long cl = hk[l][t];
            int cbig = l;
            if (l + 1 < end) {
                unsigned long long cr = hk[l + 1][t];
                if (cr > cl) { cl = cr; cbig = l + 1; }
            }
            if (v < cl) { hk[n][t] = cl; n = cbig; }
            else break;
        }
        hk[n][t] = v;
    }
    __syncthreads();

    // coalesced transposed writes: lane t writes rank t of query q0+i
    for (int i = 0; i < 64; ++i) {
        unsigned long long k = hk[t][i];
        int jloc = (int)(k & 0xFFFFFFFFULL);
        unsigned int b = (unsigned int)(k >> 32);
        b ^= ((b & 0x80000000u) ? 0x80000000u : 0xFFFFFFFFu);   // undo transform
        float d2 = __uint_as_float(b);
        int qq = q0 + i;
        outIdx [(size_t)qq * KNN + t] = (float)(seg_start + jloc);
        outDist[(size_t)qq * KNN + t] = fmaxf(d2, 0.0f);
    }
}

extern "C" void kernel_launch(void* const* d_in, const int* in_sizes, int n_in,
                              void* d_out, int out_size, void* d_ws, size_t ws_size,
                              hipStream_t stream) {
    const float* coords = (const float*)d_in[1];
    const int N = in_sizes[1] / 4;
    const int B = in_sizes[2] - 1;
    const int S = N / B;
    (void)n_in; (void)d_ws; (void)ws_size; (void)out_size;

    float* outIdx  = (float*)d_out;
    float* outDist = outIdx + (size_t)N * KNN;

    const int blocks = N / 64;
    knn_f32_kernel<<<blocks, 64, 0, stream>>>((const float4*)coords, outIdx, outDist, S);
}

// Round 18
// 758.691 us; speedup vs baseline: 3.8409x; 3.8409x over previous
//
#include <hip/hip_runtime.h>
#include <math.h>

#define KNN 64

// Value pipeline (bitwise-verified vs harness np ref in r17, absmax=0):
//   sq  = (x0^2+x2^2) + (x1^2+x3^2)   (noFMA halving butterfly)
//   dot = asc-k FMA chain
//   d2  = (sq_i + sq_j) - 2*dot       (C1)
//   ties: ascending index (stable), strict-< admission
// Parallelization: ONE WAVE PER QUERY. Top-64 kept as sorted-across-lanes
// register list (lane l = rank-l key). Per 64-candidate chunk: per-lane key,
// ballot vs uniform worst (lane63), serial shfl-insertion of survivors.
// No LDS, no heap divergence, coalesced dwordx4 candidate loads.
__global__ __launch_bounds__(256) void knn_wave_kernel(
    const float4* __restrict__ coords,
    float* __restrict__ outIdx,
    float* __restrict__ outDist,
    int S, int Nq)
{
#pragma clang fp contract(off)
    const int lane = threadIdx.x & 63;
    const int q    = (blockIdx.x << 2) + (threadIdx.x >> 6);   // 4 waves/block
    if (q >= Nq) return;                                       // no barriers used
    const int seg_start = (q / S) * S;

    const float4 x = coords[q];
    const float sqx = (x.x * x.x + x.z * x.z) + (x.y * x.y + x.w * x.w);

    unsigned long long state = ~0ULL;   // lane l holds rank-l key, sorted asc
    unsigned long long worst = ~0ULL;   // broadcast of state at lane 63

    for (int c0 = 0; c0 < S; c0 += 64) {
        const int j = c0 + lane;                       // local candidate idx
        const float4 c = coords[seg_start + j];
        const float csq = (c.x * c.x + c.z * c.z) + (c.y * c.y + c.w * c.w);
        const float dot = __builtin_fmaf(x.w, c.w,
                          __builtin_fmaf(x.z, c.z,
                          __builtin_fmaf(x.y, c.y, x.x * c.x)));
        const float t1  = sqx + csq;
        const float d2  = t1 - 2.0f * dot;
        unsigned int b = __float_as_uint(d2);
        b ^= (unsigned int)((int)b >> 31) | 0x80000000u;        // order-preserving
        const unsigned long long key =
            ((unsigned long long)b << 32) | (unsigned int)j;    // (d2, idx) lex

        unsigned long long mask = __ballot(key < worst);        // survivors
        while (mask) {
            const int s = __builtin_ctzll(mask);                // lowest idx first
            mask &= mask - 1;
            const unsigned long long cand = __shfl(key, s);     // broadcast
            if (cand >= worst) continue;                        // stale (uniform)
            // insert cand into sorted list, drop old lane-63 value
            const unsigned long long below = __ballot(state < cand);
            const int pos = __popcll(below);                    // uniform
            const unsigned long long up = __shfl_up(state, 1);
            if (lane >= pos) state = (lane == pos) ? cand : up;
            worst = __shfl(state, 63);
        }
    }

    // lane l writes rank l: fully coalesced 64-wide stores
    const int jloc = (int)(state & 0xFFFFFFFFULL);
    unsigned int b = (unsigned int)(state >> 32);
    b ^= ((b & 0x80000000u) ? 0x80000000u : 0xFFFFFFFFu);       // undo transform
    const float d2 = __uint_as_float(b);
    outIdx [(size_t)q * KNN + lane] = (float)(seg_start + jloc);
    outDist[(size_t)q * KNN + lane] = fmaxf(d2, 0.0f);
}

extern "C" void kernel_launch(void* const* d_in, const int* in_sizes, int n_in,
                              void* d_out, int out_size, void* d_ws, size_t ws_size,
                              hipStream_t stream) {
    const float* coords = (const float*)d_in[1];
    const int N = in_sizes[1] / 4;
    const int B = in_sizes[2] - 1;
    const int S = N / B;
    (void)n_in; (void)d_ws; (void)ws_size; (void)out_size;

    float* outIdx  = (float*)d_out;
    float* outDist = outIdx + (size_t)N * KNN;

    const int blocks = (N + 3) / 4;   // 4 waves (queries) per 256-thread block
    knn_wave_kernel<<<blocks, 256, 0, stream>>>((const float4*)coords,
                                                outIdx, outDist, S, N);
}

// Round 19
// 480.240 us; speedup vs baseline: 6.0678x; 1.5798x over previous
//
#include <hip/hip_runtime.h>
#include <math.h>

#define KNN 64

// Value pipeline (bitwise-verified vs harness np ref, r17 absmax=0):
//   sq  = (x0^2+x2^2) + (x1^2+x3^2)   (noFMA halving butterfly)
//   dot = asc-k FMA chain
//   d2  = (sq_i + sq_j) - 2*dot       (C1)
//   ties: ascending index (stable), strict-< admission
// r18 post-mortem: 64-bit __shfl = 2x ds_bpermute -> single per-CU LDS pipe
// saturated (~1.5M cyc/CU). This version: ZERO LDS-pipe ops in the hot loop —
// readlane (VALU) for broadcasts, DPP wave_shr:1 for the sorted-list shift,
// ballot+popc (SALU) for positions.
__device__ __forceinline__ unsigned long long dpp_shr1_u64(unsigned long long v) {
    int lo = (int)(unsigned)(v & 0xFFFFFFFFULL);
    int hi = (int)(unsigned)(v >> 32);
    // dpp_ctrl 0x138 = wave_shr:1 (gfx9-family); bound_ctrl=0 -> lane0 keeps old
    int slo = __builtin_amdgcn_update_dpp(lo, lo, 0x138, 0xF, 0xF, false);
    int shi = __builtin_amdgcn_update_dpp(hi, hi, 0x138, 0xF, 0xF, false);
    return ((unsigned long long)(unsigned)shi << 32) | (unsigned)slo;
}

__device__ __forceinline__ unsigned long long readlane_u64(unsigned long long v, int l) {
    unsigned lo = (unsigned)__builtin_amdgcn_readlane((int)(unsigned)(v & 0xFFFFFFFFULL), l);
    unsigned hi = (unsigned)__builtin_amdgcn_readlane((int)(unsigned)(v >> 32), l);
    return ((unsigned long long)hi << 32) | lo;
}

__global__ __launch_bounds__(256) void knn_wave_kernel(
    const float4* __restrict__ coords,
    float* __restrict__ outIdx,
    float* __restrict__ outDist,
    int S, int Nq)
{
#pragma clang fp contract(off)
    const int lane = threadIdx.x & 63;
    const int q    = (blockIdx.x << 2) + (threadIdx.x >> 6);   // 4 waves/block
    if (q >= Nq) return;                                       // no barriers used
    const int seg_start = (q / S) * S;

    const float4 x = coords[q];
    const float sqx = (x.x * x.x + x.z * x.z) + (x.y * x.y + x.w * x.w);

    unsigned long long state = ~0ULL;   // lane l holds rank-l key, sorted asc
    unsigned long long worst = ~0ULL;   // state at lane 63 (wave-uniform)

    for (int c0 = 0; c0 < S; c0 += 64) {
        const int j = c0 + lane;                       // local candidate idx
        const float4 c = coords[seg_start + j];
        const float csq = (c.x * c.x + c.z * c.z) + (c.y * c.y + c.w * c.w);
        const float dot = __builtin_fmaf(x.w, c.w,
                          __builtin_fmaf(x.z, c.z,
                          __builtin_fmaf(x.y, c.y, x.x * c.x)));
        const float t1  = sqx + csq;
        const float d2  = t1 - 2.0f * dot;
        unsigned int b = __float_as_uint(d2);
        b ^= (unsigned int)((int)b >> 31) | 0x80000000u;        // order-preserving
        const unsigned long long key =
            ((unsigned long long)b << 32) | (unsigned int)j;    // (d2, idx) lex

        unsigned long long mask = __ballot(key < worst);        // survivors
        while (mask) {
            const int s = __builtin_ctzll(mask);                // uniform (SALU)
            mask &= mask - 1;
            const unsigned long long cand = readlane_u64(key, s);
            if (cand >= worst) continue;                        // stale (uniform)
            // insert cand into sorted-across-lanes list, drop old rank 63
            const int pos = __popcll(__ballot(state < cand));   // uniform
            const unsigned long long up = dpp_shr1_u64(state);
            state = (lane >= pos) ? ((lane == pos) ? cand : up) : state;
            worst = readlane_u64(state, 63);
        }
    }

    // lane l writes rank l: fully coalesced 64-wide stores
    const int jloc = (int)(state & 0xFFFFFFFFULL);
    unsigned int b = (unsigned int)(state >> 32);
    b ^= ((b & 0x80000000u) ? 0x80000000u : 0xFFFFFFFFu);       // undo transform
    const float d2 = __uint_as_float(b);
    outIdx [(size_t)q * KNN + lane] = (float)(seg_start + jloc);
    outDist[(size_t)q * KNN + lane] = fmaxf(d2, 0.0f);
}

extern "C" void kernel_launch(void* const* d_in, const int* in_sizes, int n_in,
                              void* d_out, int out_size, void* d_ws, size_t ws_size,
                              hipStream_t stream) {
    const float* coords = (const float*)d_in[1];
    const int N = in_sizes[1] / 4;
    const int B = in_sizes[2] - 1;
    const int S = N / B;
    (void)n_in; (void)d_ws; (void)ws_size; (void)out_size;

    float* outIdx  = (float*)d_out;
    float* outDist = outIdx + (size_t)N * KNN;

    const int blocks = (N + 3) / 4;   // 4 waves (queries) per 256-thread block
    knn_wave_kernel<<<blocks, 256, 0, stream>>>((const float4*)coords,
                                                outIdx, outDist, S, N);
}

// Round 21
// 380.414 us; speedup vs baseline: 7.6601x; 1.2624x over previous
//
#include <hip/hip_runtime.h>
#include <math.h>

#define KNN 64

// Value pipeline (bitwise-verified vs harness np ref, r17 absmax=0):
//   sq  = (x0^2+x2^2) + (x1^2+x3^2)   (noFMA halving butterfly)
//   dot = asc-k FMA chain
//   d2  = (sq_i + sq_j) - 2*dot       (C1)
//   ties: bit-equal d2 ordered by ASCENDING index (r20 failure proved ties
//         exist under this pipeline; r18/r19 u64 key handled them).
// 32-bit sort key (sign-fixed d2 bits), idx as payload. Tie correctness via
// pos = popc(d2s <= cd): equal-valued cand inserts AFTER existing equals;
// insertion order is ascending index (ctz within chunk, chunks ascending),
// so equal-d2 runs stay index-ascending == u64-key order. Equal-to-rank-63
// cand -> pos=64 -> no-op, matching u64 boundary rule.
__device__ __forceinline__ unsigned dpp_shr1_u32(unsigned v) {
    // dpp_ctrl 0x138 = wave_shr:1; bound_ctrl=0 -> lane0 keeps old value
    return (unsigned)__builtin_amdgcn_update_dpp((int)v, (int)v, 0x138, 0xF, 0xF, false);
}

__global__ __launch_bounds__(256) void knn_wave_kernel(
    const float4* __restrict__ coords,
    float* __restrict__ outIdx,
    float* __restrict__ outDist,
    int S, int Nq)
{
#pragma clang fp contract(off)
    const int lane = threadIdx.x & 63;
    const int q    = (blockIdx.x << 2) + (threadIdx.x >> 6);   // 4 waves/block
    if (q >= Nq) return;                                       // wave-uniform
    const int seg_start = (q / S) * S;

    const float4 x = coords[q];
    const float sqx = (x.x * x.x + x.z * x.z) + (x.y * x.y + x.w * x.w);

    unsigned d2s  = 0xFFFFFFFFu;   // lane l = rank-l sign-fixed d2 bits (sorted asc)
    unsigned idxs = 0;             // payload: local candidate index
    unsigned worst = 0xFFFFFFFFu;  // d2s at lane 63 (wave-uniform scalar)

    for (int c0 = 0; c0 < S; c0 += 64) {
        const int j = c0 + lane;
        const float4 c = coords[seg_start + j];
        const float csq = (c.x * c.x + c.z * c.z) + (c.y * c.y + c.w * c.w);
        const float dot = __builtin_fmaf(x.w, c.w,
                          __builtin_fmaf(x.z, c.z,
                          __builtin_fmaf(x.y, c.y, x.x * c.x)));
        const float t1  = sqx + csq;
        const float d2  = t1 - 2.0f * dot;
        unsigned b = __float_as_uint(d2);
        b ^= (unsigned)((int)b >> 31) | 0x80000000u;            // order-preserving

        unsigned long long mask = __ballot(b < worst);          // survivors
        while (mask) {
            const int s = (int)__builtin_ctzll(mask);           // SALU, asc idx
            mask &= mask - 1;
            const unsigned cd = (unsigned)__builtin_amdgcn_readlane((int)b, s);
            const unsigned ci = (unsigned)(c0 + s);             // SALU
            const int pos = __popcll(__ballot(d2s <= cd));      // <= : after equals
            const unsigned ud = dpp_shr1_u32(d2s);
            const unsigned ui = dpp_shr1_u32(idxs);
            const bool ge = (lane >= pos);
            const bool eq = (lane == pos);
            d2s  = ge ? (eq ? cd : ud) : d2s;                   // pos=64 -> no-op
            idxs = ge ? (eq ? ci : ui) : idxs;
        }
        worst = (unsigned)__builtin_amdgcn_readlane((int)d2s, 63);  // 1x/chunk
    }

    // lane l writes rank l: fully coalesced 64-wide stores
    unsigned b = d2s;
    b ^= ((b & 0x80000000u) ? 0x80000000u : 0xFFFFFFFFu);       // undo transform
    const float d2 = __uint_as_float(b);
    outIdx [(size_t)q * KNN + lane] = (float)(seg_start + (int)idxs);
    outDist[(size_t)q * KNN + lane] = fmaxf(d2, 0.0f);
}

extern "C" void kernel_launch(void* const* d_in, const int* in_sizes, int n_in,
                              void* d_out, int out_size, void* d_ws, size_t ws_size,
                              hipStream_t stream) {
    const float* coords = (const float*)d_in[1];
    const int N = in_sizes[1] / 4;
    const int B = in_sizes[2] - 1;
    const int S = N / B;
    (void)n_in; (void)d_ws; (void)ws_size; (void)out_size;

    float* outIdx  = (float*)d_out;
    float* outDist = outIdx + (size_t)N * KNN;

    const int blocks = (N + 3) / 4;   // 4 waves (queries) per 256-thread block
    knn_wave_kernel<<<blocks, 256, 0, stream>>>((const float4*)coords,
                                                outIdx, outDist, S, N);
}